// Round 3
// baseline (233.004 us; speedup 1.0000x reference)
//
#include <hip/hip_runtime.h>

// Bilinear resample: inputs (B,S,S,C) fp32, offsets (B,S,S,2) fp32 -> out (B,S,S,C)
// B=16, S=128, C=128. Memory-bound gather, near-identity sampling grid.
//
// R3: 2 pixels per thread (8 independent gather loads in flight -> 2x memory-level
// parallelism to hide scattered-load latency). Linear block layout (R2 swizzle was
// neutral -> L2 already absorbs corner re-reads). Nontemporal output stores kept.

constexpr int S = 128;
constexpr int CVEC = 32;             // C/4 float4 groups per pixel
constexpr int PIX_PER_BLOCK = 16;    // 8 lanes-groups * 2 pixels per thread
constexpr int HALF = 8;              // pixels handled by first slot

typedef float vf4 __attribute__((ext_vector_type(4)));

__global__ __launch_bounds__(256) void resample_kernel(
    const float* __restrict__ offsets,   // (B, S, S, 2)
    const vf4*  __restrict__ inputs4,    // (B, S, S, C/4)
    vf4*        __restrict__ out4)       // (B, S, S, C/4)
{
    const int tid     = threadIdx.x;
    const int lane_c  = tid & 31;        // channel-group (0..31)
    const int pix_blk = tid >> 5;        // 0..7

    const int pix0 = blockIdx.x * PIX_PER_BLOCK + pix_blk;
    const int pix1 = pix0 + HALF;

    // Decode (b, i, j) per pixel; both pixels are in the same row.
    const int j0  = pix0 & (S - 1);
    const int j1  = pix1 & (S - 1);
    const int rem = pix0 >> 7;           // b*S + i (same for both: pix_blk<8, +8 stays in row)
    const int i   = rem & (S - 1);
    const int b   = rem >> 7;

    // Load both offset pairs up front (independent).
    const float oy0 = offsets[pix0 * 2 + 0];
    const float ox0 = offsets[pix0 * 2 + 1];
    const float oy1 = offsets[pix1 * 2 + 0];
    const float ox1 = offsets[pix1 * 2 + 1];

    const float fS1 = (float)(S - 1);
    float y0c = fminf(fmaxf((float)i  + oy0, 0.0f), fS1);
    float x0c = fminf(fmaxf((float)j0 + ox0, 0.0f), fS1);
    float y1c = fminf(fmaxf((float)i  + oy1, 0.0f), fS1);
    float x1c = fminf(fmaxf((float)j1 + ox1, 0.0f), fS1);

    const float y0f = floorf(y0c), x0f = floorf(x0c);
    const float y1f = floorf(y1c), x1f = floorf(x1c);
    const int ay0 = (int)y0f, ax0 = (int)x0f;
    const int ay1 = (int)ceilf(y0c), ax1 = (int)ceilf(x0c);
    const int by0 = (int)y1f, bx0 = (int)x1f;
    const int by1 = (int)ceilf(y1c), bx1 = (int)ceilf(x1c);
    const float afy = y0c - y0f, afx = x0c - x0f;
    const float bfy = y1c - y1f, bfx = x1c - x1f;

    const int base = (b * S * S) * CVEC + lane_c;
    const int ar0 = base + ay0 * (S * CVEC);
    const int ar1 = base + ay1 * (S * CVEC);
    const int br0 = base + by0 * (S * CVEC);
    const int br1 = base + by1 * (S * CVEC);

    // Issue all 8 gathers before any use (compiler schedules them together).
    const vf4 a00 = inputs4[ar0 + ax0 * CVEC];
    const vf4 a01 = inputs4[ar0 + ax1 * CVEC];
    const vf4 a10 = inputs4[ar1 + ax0 * CVEC];
    const vf4 a11 = inputs4[ar1 + ax1 * CVEC];
    const vf4 b00 = inputs4[br0 + bx0 * CVEC];
    const vf4 b01 = inputs4[br0 + bx1 * CVEC];
    const vf4 b10 = inputs4[br1 + bx0 * CVEC];
    const vf4 b11 = inputs4[br1 + bx1 * CVEC];

    // Reference order: lerp along x, then along y.
    const vf4 at = a00 + (a01 - a00) * afx;
    const vf4 ab = a10 + (a11 - a10) * afx;
    const vf4 ao = at + (ab - at) * afy;
    const vf4 bt = b00 + (b01 - b00) * bfx;
    const vf4 bb = b10 + (b11 - b10) * bfx;
    const vf4 bo = bt + (bb - bt) * bfy;

    __builtin_nontemporal_store(ao, &out4[(long long)pix0 * CVEC + lane_c]);
    __builtin_nontemporal_store(bo, &out4[(long long)pix1 * CVEC + lane_c]);
}

extern "C" void kernel_launch(void* const* d_in, const int* in_sizes, int n_in,
                              void* d_out, int out_size, void* d_ws, size_t ws_size,
                              hipStream_t stream) {
    const float* offsets = (const float*)d_in[0];
    const vf4*   inputs4 = (const vf4*)d_in[1];
    vf4*         out4    = (vf4*)d_out;

    const int B = in_sizes[0] / (S * S * 2);       // = 16
    const int total_pix = B * S * S;               // 262144
    const int blocks = total_pix / PIX_PER_BLOCK;  // 16384

    resample_kernel<<<blocks, 256, 0, stream>>>(offsets, inputs4, out4);
}